// Round 8
// baseline (1207.632 us; speedup 1.0000x reference)
//
#include <hip/hip_runtime.h>

#define NN 150000
#define NE 600000
#define NG 5000
#define H 128
#define NOFF (NN + 1)
#define NBLK 147   // ceil(150001 / 1024)
#define NSPLIT 64  // stats_part split factor

typedef short bf16x8 __attribute__((ext_vector_type(8)));
typedef float f32x4 __attribute__((ext_vector_type(4)));

__device__ __forceinline__ unsigned short f2bf(float f) {
    unsigned u = __builtin_bit_cast(unsigned, f);
    u += 0x7fffu + ((u >> 16) & 1u);
    return (unsigned short)(u >> 16);
}
__device__ __forceinline__ float bf2f(unsigned short u) {
    return __builtin_bit_cast(float, (unsigned)u << 16);
}

// h = bf16(x @ Wn + bn_b)   [NN,6]@[6,H]
__global__ __launch_bounds__(256) void encoder_k(const float* __restrict__ x,
                                                 const float* __restrict__ Wn,
                                                 const float* __restrict__ bn_b,
                                                 unsigned short* __restrict__ h) {
    int t = blockIdx.x * 256 + threadIdx.x;   // over NN*H
    int i = t >> 7, j = t & 127;
    float acc = bn_b[j];
#pragma unroll
    for (int k = 0; k < 6; k++) acc += x[i * 6 + k] * Wn[k * H + j];
    h[t] = f2bf(acc);
}

// ---------- weight prepack: bf16, MFMA-fragment order ----------
// mat m in [0,11): 0-3 W1[l], 4-7 W2[l], 8 Wo1, 9 Wo2 cols 0-127, 10 Wo2 cols 128-255
// chunk flat=(c*4+kk)*64+lane holds 8 shorts: W^T[n=c*16+(lane&15)][k=kk*32+(lane>>4)*8 .. +8]
__global__ __launch_bounds__(256) void prepack_k(const float* __restrict__ W1,
                                                 const float* __restrict__ W2,
                                                 const float* __restrict__ Wo1,
                                                 const float* __restrict__ Wo2,
                                                 unsigned short* __restrict__ Wf) {
    int m = blockIdx.x;
    const float* W; int ld, col0;
    if (m < 4)       { W = W1 + m * 16384;      ld = 128; col0 = 0; }
    else if (m < 8)  { W = W2 + (m - 4) * 16384; ld = 128; col0 = 0; }
    else if (m == 8) { W = Wo1;                  ld = 128; col0 = 0; }
    else if (m == 9) { W = Wo2;                  ld = 256; col0 = 0; }
    else             { W = Wo2;                  ld = 256; col0 = 128; }
    unsigned short* dst = Wf + m * 16384;
    for (int flat = threadIdx.x; flat < 2048; flat += 256) {
        int c = flat >> 8, kk = (flat >> 6) & 3, lane = flat & 63;
        int n = col0 + c * 16 + (lane & 15);
        int k0 = kk * 32 + (lane >> 4) * 8;
        ushort4 lo, hi;
        lo.x = f2bf(W[(size_t)(k0 + 0) * ld + n]);
        lo.y = f2bf(W[(size_t)(k0 + 1) * ld + n]);
        lo.z = f2bf(W[(size_t)(k0 + 2) * ld + n]);
        lo.w = f2bf(W[(size_t)(k0 + 3) * ld + n]);
        hi.x = f2bf(W[(size_t)(k0 + 4) * ld + n]);
        hi.y = f2bf(W[(size_t)(k0 + 5) * ld + n]);
        hi.z = f2bf(W[(size_t)(k0 + 6) * ld + n]);
        hi.w = f2bf(W[(size_t)(k0 + 7) * ld + n]);
        *(ushort4*)&dst[flat * 8]     = lo;
        *(ushort4*)&dst[flat * 8 + 4] = hi;
    }
}

// ---------- CSR build: histogram -> exclusive scan -> fill ----------

__global__ __launch_bounds__(256) void hist_k(const int* __restrict__ ei,
                                              int* __restrict__ deg) {
    int e = blockIdx.x * 256 + threadIdx.x;
    if (e < NE) atomicAdd(&deg[ei[NE + e]], 1);
}

__global__ __launch_bounds__(256) void scan1_k(const int* __restrict__ deg,
                                               int* __restrict__ part,
                                               int* __restrict__ bsum) {
    __shared__ int ls[256];
    int tid = threadIdx.x;
    int base = blockIdx.x * 1024 + tid * 4;
    int v[4], s = 0;
#pragma unroll
    for (int j = 0; j < 4; j++) {
        int idx = base + j;
        v[j] = (idx < NN) ? deg[idx] : 0;
        s += v[j];
    }
    ls[tid] = s;
    __syncthreads();
    for (int off = 1; off < 256; off <<= 1) {
        int t2 = (tid >= off) ? ls[tid - off] : 0;
        __syncthreads();
        if (tid >= off) ls[tid] += t2;
        __syncthreads();
    }
    int run = ls[tid] - s;
#pragma unroll
    for (int j = 0; j < 4; j++) {
        int idx = base + j;
        if (idx < NOFF) part[idx] = run;
        run += v[j];
    }
    if (tid == 255) bsum[blockIdx.x] = ls[255];
}

__global__ __launch_bounds__(256) void scan2_k(int* __restrict__ bsum) {
    __shared__ int ls[256];
    int tid = threadIdx.x;
    int v = (tid < NBLK) ? bsum[tid] : 0;
    ls[tid] = v;
    __syncthreads();
    for (int off = 1; off < 256; off <<= 1) {
        int t2 = (tid >= off) ? ls[tid - off] : 0;
        __syncthreads();
        if (tid >= off) ls[tid] += t2;
        __syncthreads();
    }
    if (tid < NBLK) bsum[tid] = ls[tid] - v;
}

__global__ __launch_bounds__(256) void scan3_k(const int* __restrict__ part,
                                               const int* __restrict__ bsum,
                                               int* __restrict__ offsets,
                                               int* __restrict__ cursor) {
    int tid = threadIdx.x;
    int base = blockIdx.x * 1024 + tid * 4;
    int bs = bsum[blockIdx.x];
#pragma unroll
    for (int j = 0; j < 4; j++) {
        int idx = base + j;
        if (idx < NOFF) {
            int o = part[idx] + bs;
            offsets[idx] = o;
            if (idx < NN) cursor[idx] = o;
        }
    }
}

__global__ __launch_bounds__(256) void fill_k(const int* __restrict__ ei,
                                              int* __restrict__ cursor,
                                              int* __restrict__ adj) {
    int e = blockIdx.x * 256 + threadIdx.x;
    if (e < NE) {
        int p = atomicAdd(&cursor[ei[NE + e]], 1);
        if (p >= 0 && p < NE) adj[p] = ei[e];
    }
}

// ---------- fused GIN layer part 1: gather into LDS + MFMA with W1 ----------
// t = bf16(relu( ((1+eps)h + sum_nbr h) @ W1 + b1 ))
__global__ __launch_bounds__(256) void gin1_k(const unsigned short* __restrict__ h,
                                              const int* __restrict__ offsets,
                                              const int* __restrict__ adj,
                                              const float* __restrict__ eps, int l,
                                              const unsigned short* __restrict__ Wf,
                                              const float* __restrict__ bias,
                                              unsigned short* __restrict__ C, int M,
                                              float* __restrict__ stats_part) {
    __shared__ short Wlds[16384];      // fragment-order W
    __shared__ short Alds[64 * 136];   // gathered rows, +8 short pad
    int tid = threadIdx.x;
    if (blockIdx.x < NSPLIT) stats_part[blockIdx.x * 256 + tid] = 0.f;  // for gemm2
#pragma unroll
    for (int i = 0; i < 8; i++) {
        int flat = i * 256 + tid;
        ((bf16x8*)Wlds)[flat] = ((const bf16x8*)Wf)[flat];
    }

    // gather phase: one full wave per row (wave-uniform adj loop), 16 rows/wave
    int wv = tid >> 6, lane = tid & 63;
    float e = 1.f + eps[l];
    const ushort2* hp = (const ushort2*)h;   // row = 64 ushort2
    for (int r = 0; r < 16; r++) {
        int lrow = wv * 16 + r;
        int i = blockIdx.x * 64 + lrow;
        float a0 = 0.f, a1 = 0.f;
        if (i < M) {
            ushort2 sv = hp[(size_t)i * 64 + lane];
            a0 = bf2f(sv.x) * e; a1 = bf2f(sv.y) * e;
            int s0 = offsets[i], s1 = offsets[i + 1];
            for (int k = s0; k < s1; k++) {
                ushort2 v = hp[(size_t)adj[k] * 64 + lane];
                a0 += bf2f(v.x); a1 += bf2f(v.y);
            }
        }
        ushort2 o; o.x = f2bf(a0); o.y = f2bf(a1);
        *(ushort2*)&Alds[lrow * 136 + lane * 2] = o;
    }
    __syncthreads();

    // MFMA phase
    int w = tid >> 6, lane2 = tid & 63;
    int quad = lane2 >> 4, lr = lane2 & 15;
    f32x4 acc[8];
#pragma unroll
    for (int c = 0; c < 8; c++) acc[c] = (f32x4){0.f, 0.f, 0.f, 0.f};
#pragma unroll
    for (int kk = 0; kk < 4; kk++) {
        bf16x8 af = *(const bf16x8*)&Alds[(w * 16 + lr) * 136 + kk * 32 + quad * 8];
#pragma unroll
        for (int c = 0; c < 8; c++) {
            bf16x8 bf = ((const bf16x8*)Wlds)[(c * 4 + kk) * 64 + lane2];
            acc[c] = __builtin_amdgcn_mfma_f32_16x16x32_bf16(af, bf, acc[c], 0, 0, 0);
        }
    }

    int r0 = blockIdx.x * 64 + w * 16 + quad * 4;
#pragma unroll
    for (int c = 0; c < 8; c++) {
        int col = c * 16 + lr;
        float bv = bias[col];
#pragma unroll
        for (int r = 0; r < 4; r++) {
            int row = r0 + r;
            if (row < M)
                C[(size_t)row * H + col] = f2bf(fmaxf(acc[c][r] + bv, 0.f));
        }
    }
}

// C[M,128] = op(bf16 A[M,128] @ Wf + bias); Wf prepacked fragment-order bf16.
// optional bf16 out, fused BN stats (wave-reduced over quads).
template <bool RELU, bool OBF16, bool STATS>
__global__ __launch_bounds__(256) void gemm128f(const unsigned short* __restrict__ A,
                                                const unsigned short* __restrict__ Wf,
                                                const float* __restrict__ bias,
                                                void* __restrict__ Cv, int ldC, int M,
                                                float* __restrict__ stats_part) {
    __shared__ short Wlds[16384];   // fragment-order: chunk flat=(c*4+kk)*64+lane
    __shared__ float sst[256];
    int tid = threadIdx.x;
#pragma unroll
    for (int i = 0; i < 8; i++) {
        int flat = i * 256 + tid;
        ((bf16x8*)Wlds)[flat] = ((const bf16x8*)Wf)[flat];
    }
    if (STATS) sst[tid] = 0.f;
    __syncthreads();

    int w = tid >> 6, lane = tid & 63;
    int quad = lane >> 4, lr = lane & 15;
    int rowA = blockIdx.x * 64 + w * 16 + lr;
    bool rowOK = rowA < M;
    const unsigned short* ap = A + (size_t)rowA * 128 + quad * 8;

    f32x4 acc[8];
#pragma unroll
    for (int c = 0; c < 8; c++) acc[c] = (f32x4){0.f, 0.f, 0.f, 0.f};

#pragma unroll
    for (int kk = 0; kk < 4; kk++) {
        bf16x8 af = rowOK ? *(const bf16x8*)(ap + kk * 32)
                          : (bf16x8){0, 0, 0, 0, 0, 0, 0, 0};
#pragma unroll
        for (int c = 0; c < 8; c++) {
            bf16x8 bf = ((const bf16x8*)Wlds)[(c * 4 + kk) * 64 + lane];
            acc[c] = __builtin_amdgcn_mfma_f32_16x16x32_bf16(af, bf, acc[c], 0, 0, 0);
        }
    }

    int r0 = blockIdx.x * 64 + w * 16 + quad * 4;
#pragma unroll
    for (int c = 0; c < 8; c++) {
        int col = c * 16 + lr;
        float bv = bias[col];
        float ls = 0.f, ls2 = 0.f;
#pragma unroll
        for (int r = 0; r < 4; r++) {
            int row = r0 + r;
            if (row < M) {
                float v = acc[c][r] + bv;
                if (RELU) v = fmaxf(v, 0.f);
                if (OBF16)
                    ((unsigned short*)Cv)[(size_t)row * ldC + col] = f2bf(v);
                else
                    ((float*)Cv)[(size_t)row * ldC + col] = v;
                if (STATS) { ls += v; ls2 += v * v; }
            }
        }
        if (STATS) {
            ls  += __shfl_xor(ls, 16);  ls  += __shfl_xor(ls, 32);
            ls2 += __shfl_xor(ls2, 16); ls2 += __shfl_xor(ls2, 32);
            if (quad == 0) {
                atomicAdd(&sst[col], ls);
                atomicAdd(&sst[128 + col], ls2);
            }
        }
    }
    if (STATS) {
        __syncthreads();
        atomicAdd(&stats_part[(blockIdx.x & (NSPLIT - 1)) * 256 + tid], sst[tid]);
    }
}

// reduce stats_part -> coef[c]=gamma*istd, coef[128+c]=beta-mu*gamma*istd
__global__ __launch_bounds__(256) void finalize_stats_k(const float* __restrict__ stats_part,
                                                        const float* __restrict__ gamma,
                                                        const float* __restrict__ beta,
                                                        float* __restrict__ coef, float invN) {
    __shared__ float ls[256];
    int t = threadIdx.x;
    float s = 0.f;
    for (int p = 0; p < NSPLIT; p++) s += stats_part[p * 256 + t];
    ls[t] = s;
    __syncthreads();
    if (t < 128) {
        float mu = ls[t] * invN;
        float var = ls[128 + t] * invN - mu * mu;
        float a = gamma[t] * rsqrtf(var + 1e-5f);
        coef[t] = a;
        coef[128 + t] = beta[t] - mu * a;
    }
}

// h = bf16(relu(m*a + b) + h)   (m stored bf16)
__global__ __launch_bounds__(256) void bn_apply_k(const unsigned short* __restrict__ m,
                                                  const float* __restrict__ coef,
                                                  unsigned short* __restrict__ h) {
    int t = blockIdx.x * 256 + threadIdx.x;   // NN*32, 4 cols per thread
    int c4 = t & 31;
    float4 a = ((const float4*)coef)[c4];
    float4 b = ((const float4*)coef)[32 + c4];
    ushort4 mv = ((const ushort4*)m)[t];
    ushort4 hv = ((const ushort4*)h)[t];
    float h0 = bf2f(hv.x) + fmaxf(bf2f(mv.x) * a.x + b.x, 0.f);
    float h1 = bf2f(hv.y) + fmaxf(bf2f(mv.y) * a.y + b.y, 0.f);
    float h2 = bf2f(hv.z) + fmaxf(bf2f(mv.z) * a.z + b.z, 0.f);
    float h3 = bf2f(hv.w) + fmaxf(bf2f(mv.w) * a.w + b.w, 0.f);
    ushort4 o;
    o.x = f2bf(h0); o.y = f2bf(h1); o.z = f2bf(h2); o.w = f2bf(h3);
    ((ushort4*)h)[t] = o;
}

// ---------- pooling (batch is sorted) ----------

__global__ __launch_bounds__(256) void gbound_k(const int* __restrict__ batch,
                                                int* __restrict__ gstart) {
    int i = blockIdx.x * 256 + threadIdx.x;
    if (i >= NN) return;
    int b = batch[i];
    int prev = (i == 0) ? -1 : batch[i - 1];
    for (int g = prev + 1; g <= b; g++) gstart[g] = i;
    if (i == NN - 1) {
        for (int g = b + 1; g <= NG; g++) gstart[g] = NN;
    }
}

// one block per graph: mean over its node rows -> bf16 pooled
__global__ __launch_bounds__(128) void pool_k(const unsigned short* __restrict__ h,
                                              const int* __restrict__ gstart,
                                              unsigned short* __restrict__ pooled) {
    int g = blockIdx.x, col = threadIdx.x;
    int r0 = gstart[g], r1 = gstart[g + 1];
    float s = 0.f;
    for (int r = r0; r < r1; r++) s += bf2f(h[(size_t)r * H + col]);
    pooled[(size_t)g * H + col] = f2bf(s / fmaxf((float)(r1 - r0), 1.f));
}

extern "C" void kernel_launch(void* const* d_in, const int* in_sizes, int n_in,
                              void* d_out, int out_size, void* d_ws, size_t ws_size,
                              hipStream_t stream) {
    const float* x     = (const float*)d_in[0];
    const int*   ei    = (const int*)d_in[1];
    const int*   batch = (const int*)d_in[2];
    const float* Wn    = (const float*)d_in[3];
    const float* bn_b  = (const float*)d_in[4];
    const float* eps   = (const float*)d_in[5];
    const float* W1    = (const float*)d_in[6];
    const float* b1    = (const float*)d_in[7];
    const float* W2    = (const float*)d_in[8];
    const float* b2    = (const float*)d_in[9];
    const float* gamma = (const float*)d_in[10];
    const float* beta  = (const float*)d_in[11];
    const float* Wo1   = (const float*)d_in[12];
    const float* bo1   = (const float*)d_in[13];
    const float* Wo2   = (const float*)d_in[14];
    const float* bo2   = (const float*)d_in[15];
    float* out = (float*)d_out;

    // ---- workspace: ~120 MB total ----
    unsigned short* h   = (unsigned short*)d_ws;                   // NN*H bf16
    unsigned short* m   = h + (size_t)NN * H;                      // NN*H bf16
    unsigned short* tB  = m + (size_t)NN * H;                      // NN*H bf16
    float* stats_part   = (float*)(tB + (size_t)NN * H);           // NSPLIT*256
    float* coef         = stats_part + NSPLIT * 256;               // 256
    unsigned short* Wf  = (unsigned short*)(coef + 256);           // 11*16384 bf16
    unsigned short* pooledB = Wf + 11 * 16384;                     // NG*H bf16
    int* offsets = (int*)(pooledB + (size_t)NG * H);               // NOFF
    int* adj     = offsets + NOFF;                                 // NE
    int* gstart  = adj + NE;                                       // NG+1
    // transient CSR-build arrays overlaid in m (m is first written by layer-0
    // gemm2, strictly after the CSR build on the same stream)
    int* deg    = (int*)m;         // NN
    int* part   = deg + NN;        // NOFF
    int* bsum   = part + NOFF;     // 256
    int* cursor = bsum + 256;      // NN

    // weight prepack + CSR build (once; reused by all 4 layers)
    prepack_k<<<11, 256, 0, stream>>>(W1, W2, Wo1, Wo2, Wf);
    hipMemsetAsync(deg, 0, NN * sizeof(int), stream);
    hist_k<<<2344, 256, 0, stream>>>(ei, deg);
    scan1_k<<<NBLK, 256, 0, stream>>>(deg, part, bsum);
    scan2_k<<<1, 256, 0, stream>>>(bsum);
    scan3_k<<<NBLK, 256, 0, stream>>>(part, bsum, offsets, cursor);
    fill_k<<<2344, 256, 0, stream>>>(ei, cursor, adj);
    gbound_k<<<586, 256, 0, stream>>>(batch, gstart);

    encoder_k<<<75000, 256, 0, stream>>>(x, Wn, bn_b, h);

    for (int l = 0; l < 4; l++) {
        gin1_k<<<2344, 256, 0, stream>>>(h, offsets, adj, eps, l,
                                         Wf + l * 16384, b1 + l * 128, tB, NN,
                                         stats_part);
        gemm128f<false, true, true><<<2344, 256, 0, stream>>>(
            tB, Wf + (4 + l) * 16384, b2 + l * 128, m, 128, NN, stats_part);
        finalize_stats_k<<<1, 256, 0, stream>>>(stats_part, gamma + l * 128,
                                                beta + l * 128, coef, 1.f / NN);
        bn_apply_k<<<18750, 256, 0, stream>>>(m, coef, h);
    }

    pool_k<<<NG, 128, 0, stream>>>(h, gstart, pooledB);

    gemm128f<true, true, false><<<79, 256, 0, stream>>>(
        pooledB, Wf + 8 * 16384, bo1, tB, 128, NG, nullptr);
    gemm128f<false, false, false><<<79, 256, 0, stream>>>(
        tB, Wf + 9 * 16384, bo2, out, 256, NG, nullptr);
    gemm128f<false, false, false><<<79, 256, 0, stream>>>(
        tB, Wf + 10 * 16384, bo2 + 128, out + 128, 256, NG, nullptr);
}

// Round 9
// 768.734 us; speedup vs baseline: 1.5709x; 1.5709x over previous
//
#include <hip/hip_runtime.h>

#define NN 150000
#define NE 600000
#define NG 5000
#define H 128
#define NOFF (NN + 1)
#define NBLK 147   // ceil(150001 / 1024)
#define NSPLIT 64  // stats_part split factor

typedef short bf16x8 __attribute__((ext_vector_type(8)));
typedef float f32x4 __attribute__((ext_vector_type(4)));

__device__ __forceinline__ unsigned short f2bf(float f) {
    unsigned u = __builtin_bit_cast(unsigned, f);
    u += 0x7fffu + ((u >> 16) & 1u);
    return (unsigned short)(u >> 16);
}
__device__ __forceinline__ float bf2f(unsigned short u) {
    return __builtin_bit_cast(float, (unsigned)u << 16);
}

// h = bf16(x @ Wn + bn_b)   [NN,6]@[6,H]
__global__ __launch_bounds__(256) void encoder_k(const float* __restrict__ x,
                                                 const float* __restrict__ Wn,
                                                 const float* __restrict__ bn_b,
                                                 unsigned short* __restrict__ h) {
    int t = blockIdx.x * 256 + threadIdx.x;   // over NN*H
    int i = t >> 7, j = t & 127;
    float acc = bn_b[j];
#pragma unroll
    for (int k = 0; k < 6; k++) acc += x[i * 6 + k] * Wn[k * H + j];
    h[t] = f2bf(acc);
}

// ---------- weight prepack: bf16, MFMA-fragment order ----------
// mat m in [0,11): 0-3 W1[l], 4-7 W2[l], 8 Wo1, 9 Wo2 cols 0-127, 10 Wo2 cols 128-255
// chunk flat=(c*4+kk)*64+lane holds 8 shorts: W^T[n=c*16+(lane&15)][k=kk*32+(lane>>4)*8 .. +8]
__global__ __launch_bounds__(256) void prepack_k(const float* __restrict__ W1,
                                                 const float* __restrict__ W2,
                                                 const float* __restrict__ Wo1,
                                                 const float* __restrict__ Wo2,
                                                 unsigned short* __restrict__ Wf) {
    int m = blockIdx.x;
    const float* W; int ld, col0;
    if (m < 4)       { W = W1 + m * 16384;      ld = 128; col0 = 0; }
    else if (m < 8)  { W = W2 + (m - 4) * 16384; ld = 128; col0 = 0; }
    else if (m == 8) { W = Wo1;                  ld = 128; col0 = 0; }
    else if (m == 9) { W = Wo2;                  ld = 256; col0 = 0; }
    else             { W = Wo2;                  ld = 256; col0 = 128; }
    unsigned short* dst = Wf + m * 16384;
    for (int flat = threadIdx.x; flat < 2048; flat += 256) {
        int c = flat >> 8, kk = (flat >> 6) & 3, lane = flat & 63;
        int n = col0 + c * 16 + (lane & 15);
        int k0 = kk * 32 + (lane >> 4) * 8;
        ushort4 lo, hi;
        lo.x = f2bf(W[(size_t)(k0 + 0) * ld + n]);
        lo.y = f2bf(W[(size_t)(k0 + 1) * ld + n]);
        lo.z = f2bf(W[(size_t)(k0 + 2) * ld + n]);
        lo.w = f2bf(W[(size_t)(k0 + 3) * ld + n]);
        hi.x = f2bf(W[(size_t)(k0 + 4) * ld + n]);
        hi.y = f2bf(W[(size_t)(k0 + 5) * ld + n]);
        hi.z = f2bf(W[(size_t)(k0 + 6) * ld + n]);
        hi.w = f2bf(W[(size_t)(k0 + 7) * ld + n]);
        *(ushort4*)&dst[flat * 8]     = lo;
        *(ushort4*)&dst[flat * 8 + 4] = hi;
    }
}

// ---------- CSR build: histogram -> exclusive scan -> fill ----------

__global__ __launch_bounds__(256) void hist_k(const int* __restrict__ ei,
                                              int* __restrict__ deg) {
    int e = blockIdx.x * 256 + threadIdx.x;
    if (e < NE) atomicAdd(&deg[ei[NE + e]], 1);
}

__global__ __launch_bounds__(256) void scan1_k(const int* __restrict__ deg,
                                               int* __restrict__ part,
                                               int* __restrict__ bsum) {
    __shared__ int ls[256];
    int tid = threadIdx.x;
    int base = blockIdx.x * 1024 + tid * 4;
    int v[4], s = 0;
#pragma unroll
    for (int j = 0; j < 4; j++) {
        int idx = base + j;
        v[j] = (idx < NN) ? deg[idx] : 0;
        s += v[j];
    }
    ls[tid] = s;
    __syncthreads();
    for (int off = 1; off < 256; off <<= 1) {
        int t2 = (tid >= off) ? ls[tid - off] : 0;
        __syncthreads();
        if (tid >= off) ls[tid] += t2;
        __syncthreads();
    }
    int run = ls[tid] - s;
#pragma unroll
    for (int j = 0; j < 4; j++) {
        int idx = base + j;
        if (idx < NOFF) part[idx] = run;
        run += v[j];
    }
    if (tid == 255) bsum[blockIdx.x] = ls[255];
}

__global__ __launch_bounds__(256) void scan2_k(int* __restrict__ bsum) {
    __shared__ int ls[256];
    int tid = threadIdx.x;
    int v = (tid < NBLK) ? bsum[tid] : 0;
    ls[tid] = v;
    __syncthreads();
    for (int off = 1; off < 256; off <<= 1) {
        int t2 = (tid >= off) ? ls[tid - off] : 0;
        __syncthreads();
        if (tid >= off) ls[tid] += t2;
        __syncthreads();
    }
    if (tid < NBLK) bsum[tid] = ls[tid] - v;
}

__global__ __launch_bounds__(256) void scan3_k(const int* __restrict__ part,
                                               const int* __restrict__ bsum,
                                               int* __restrict__ offsets,
                                               int* __restrict__ cursor) {
    int tid = threadIdx.x;
    int base = blockIdx.x * 1024 + tid * 4;
    int bs = bsum[blockIdx.x];
#pragma unroll
    for (int j = 0; j < 4; j++) {
        int idx = base + j;
        if (idx < NOFF) {
            int o = part[idx] + bs;
            offsets[idx] = o;
            if (idx < NN) cursor[idx] = o;
        }
    }
}

__global__ __launch_bounds__(256) void fill_k(const int* __restrict__ ei,
                                              int* __restrict__ cursor,
                                              int* __restrict__ adj) {
    int e = blockIdx.x * 256 + threadIdx.x;
    if (e < NE) {
        int p = atomicAdd(&cursor[ei[NE + e]], 1);
        if (p >= 0 && p < NE) adj[p] = ei[e];
    }
}

// ---------- gather: agg = bf16((1+eps)*h + sum_{j->i} h[j]), fp32 accum ----------
__global__ __launch_bounds__(256) void gather_k(const unsigned short* __restrict__ h,
                                                const int* __restrict__ offsets,
                                                const int* __restrict__ adj,
                                                const float* __restrict__ eps, int l,
                                                unsigned short* __restrict__ agg,
                                                float* __restrict__ stats_part) {
    if (blockIdx.x < NSPLIT) stats_part[blockIdx.x * 256 + threadIdx.x] = 0.f;
    int t = blockIdx.x * 256 + threadIdx.x;   // NN*32, 4 cols per thread
    int i = t >> 5, q = t & 31;
    const ushort4* hp = (const ushort4*)h;
    float e = 1.f + eps[l];
    ushort4 sv = hp[(size_t)i * 32 + q];
    float a0 = bf2f(sv.x) * e, a1 = bf2f(sv.y) * e, a2 = bf2f(sv.z) * e, a3 = bf2f(sv.w) * e;
    int s0 = offsets[i], s1 = offsets[i + 1];
    for (int k = s0; k < s1; k++) {
        int src = adj[k];
        ushort4 v = hp[(size_t)src * 32 + q];
        a0 += bf2f(v.x); a1 += bf2f(v.y); a2 += bf2f(v.z); a3 += bf2f(v.w);
    }
    ushort4 o;
    o.x = f2bf(a0); o.y = f2bf(a1); o.z = f2bf(a2); o.w = f2bf(a3);
    ((ushort4*)agg)[(size_t)i * 32 + q] = o;
}

// C[M,128] = op(bf16 A[M,128] @ Wf + bias); Wf prepacked fragment-order bf16.
// optional bf16 out, fused BN stats (wave-reduced over quads).
template <bool RELU, bool OBF16, bool STATS>
__global__ __launch_bounds__(256) void gemm128f(const unsigned short* __restrict__ A,
                                                const unsigned short* __restrict__ Wf,
                                                const float* __restrict__ bias,
                                                void* __restrict__ Cv, int ldC, int M,
                                                float* __restrict__ stats_part) {
    __shared__ short Wlds[16384];   // fragment-order: chunk flat=(c*4+kk)*64+lane
    __shared__ float sst[256];
    int tid = threadIdx.x;
#pragma unroll
    for (int i = 0; i < 8; i++) {
        int flat = i * 256 + tid;
        ((bf16x8*)Wlds)[flat] = ((const bf16x8*)Wf)[flat];
    }
    if (STATS) sst[tid] = 0.f;
    __syncthreads();

    int w = tid >> 6, lane = tid & 63;
    int quad = lane >> 4, lr = lane & 15;
    int rowA = blockIdx.x * 64 + w * 16 + lr;
    bool rowOK = rowA < M;
    const unsigned short* ap = A + (size_t)rowA * 128 + quad * 8;

    f32x4 acc[8];
#pragma unroll
    for (int c = 0; c < 8; c++) acc[c] = (f32x4){0.f, 0.f, 0.f, 0.f};

#pragma unroll
    for (int kk = 0; kk < 4; kk++) {
        bf16x8 af = rowOK ? *(const bf16x8*)(ap + kk * 32)
                          : (bf16x8){0, 0, 0, 0, 0, 0, 0, 0};
#pragma unroll
        for (int c = 0; c < 8; c++) {
            bf16x8 bf = ((const bf16x8*)Wlds)[(c * 4 + kk) * 64 + lane];
            acc[c] = __builtin_amdgcn_mfma_f32_16x16x32_bf16(af, bf, acc[c], 0, 0, 0);
        }
    }

    int r0 = blockIdx.x * 64 + w * 16 + quad * 4;
#pragma unroll
    for (int c = 0; c < 8; c++) {
        int col = c * 16 + lr;
        float bv = bias[col];
        float ls = 0.f, ls2 = 0.f;
#pragma unroll
        for (int r = 0; r < 4; r++) {
            int row = r0 + r;
            if (row < M) {
                float v = acc[c][r] + bv;
                if (RELU) v = fmaxf(v, 0.f);
                if (OBF16)
                    ((unsigned short*)Cv)[(size_t)row * ldC + col] = f2bf(v);
                else
                    ((float*)Cv)[(size_t)row * ldC + col] = v;
                if (STATS) { ls += v; ls2 += v * v; }
            }
        }
        if (STATS) {
            ls  += __shfl_xor(ls, 16);  ls  += __shfl_xor(ls, 32);
            ls2 += __shfl_xor(ls2, 16); ls2 += __shfl_xor(ls2, 32);
            if (quad == 0) {
                atomicAdd(&sst[col], ls);
                atomicAdd(&sst[128 + col], ls2);
            }
        }
    }
    if (STATS) {
        __syncthreads();
        atomicAdd(&stats_part[(blockIdx.x & (NSPLIT - 1)) * 256 + tid], sst[tid]);
    }
}

// reduce stats_part -> coef[c]=gamma*istd, coef[128+c]=beta-mu*gamma*istd
__global__ __launch_bounds__(256) void finalize_stats_k(const float* __restrict__ stats_part,
                                                        const float* __restrict__ gamma,
                                                        const float* __restrict__ beta,
                                                        float* __restrict__ coef, float invN) {
    __shared__ float ls[256];
    int t = threadIdx.x;
    float s = 0.f;
    for (int p = 0; p < NSPLIT; p++) s += stats_part[p * 256 + t];
    ls[t] = s;
    __syncthreads();
    if (t < 128) {
        float mu = ls[t] * invN;
        float var = ls[128 + t] * invN - mu * mu;
        float a = gamma[t] * rsqrtf(var + 1e-5f);
        coef[t] = a;
        coef[128 + t] = beta[t] - mu * a;
    }
}

// h = bf16(relu(m*a + b) + h)   (m stored bf16)
__global__ __launch_bounds__(256) void bn_apply_k(const unsigned short* __restrict__ m,
                                                  const float* __restrict__ coef,
                                                  unsigned short* __restrict__ h) {
    int t = blockIdx.x * 256 + threadIdx.x;   // NN*32, 4 cols per thread
    int c4 = t & 31;
    float4 a = ((const float4*)coef)[c4];
    float4 b = ((const float4*)coef)[32 + c4];
    ushort4 mv = ((const ushort4*)m)[t];
    ushort4 hv = ((const ushort4*)h)[t];
    float h0 = bf2f(hv.x) + fmaxf(bf2f(mv.x) * a.x + b.x, 0.f);
    float h1 = bf2f(hv.y) + fmaxf(bf2f(mv.y) * a.y + b.y, 0.f);
    float h2 = bf2f(hv.z) + fmaxf(bf2f(mv.z) * a.z + b.z, 0.f);
    float h3 = bf2f(hv.w) + fmaxf(bf2f(mv.w) * a.w + b.w, 0.f);
    ushort4 o;
    o.x = f2bf(h0); o.y = f2bf(h1); o.z = f2bf(h2); o.w = f2bf(h3);
    ((ushort4*)h)[t] = o;
}

// ---------- pooling (batch is sorted) ----------

__global__ __launch_bounds__(256) void gbound_k(const int* __restrict__ batch,
                                                int* __restrict__ gstart) {
    int i = blockIdx.x * 256 + threadIdx.x;
    if (i >= NN) return;
    int b = batch[i];
    int prev = (i == 0) ? -1 : batch[i - 1];
    for (int g = prev + 1; g <= b; g++) gstart[g] = i;
    if (i == NN - 1) {
        for (int g = b + 1; g <= NG; g++) gstart[g] = NN;
    }
}

// one block per graph: mean over its node rows -> bf16 pooled
__global__ __launch_bounds__(128) void pool_k(const unsigned short* __restrict__ h,
                                              const int* __restrict__ gstart,
                                              unsigned short* __restrict__ pooled) {
    int g = blockIdx.x, col = threadIdx.x;
    int r0 = gstart[g], r1 = gstart[g + 1];
    float s = 0.f;
    for (int r = r0; r < r1; r++) s += bf2f(h[(size_t)r * H + col]);
    pooled[(size_t)g * H + col] = f2bf(s / fmaxf((float)(r1 - r0), 1.f));
}

extern "C" void kernel_launch(void* const* d_in, const int* in_sizes, int n_in,
                              void* d_out, int out_size, void* d_ws, size_t ws_size,
                              hipStream_t stream) {
    const float* x     = (const float*)d_in[0];
    const int*   ei    = (const int*)d_in[1];
    const int*   batch = (const int*)d_in[2];
    const float* Wn    = (const float*)d_in[3];
    const float* bn_b  = (const float*)d_in[4];
    const float* eps   = (const float*)d_in[5];
    const float* W1    = (const float*)d_in[6];
    const float* b1    = (const float*)d_in[7];
    const float* W2    = (const float*)d_in[8];
    const float* b2    = (const float*)d_in[9];
    const float* gamma = (const float*)d_in[10];
    const float* beta  = (const float*)d_in[11];
    const float* Wo1   = (const float*)d_in[12];
    const float* bo1   = (const float*)d_in[13];
    const float* Wo2   = (const float*)d_in[14];
    const float* bo2   = (const float*)d_in[15];
    float* out = (float*)d_out;

    // ---- workspace: ~160 MB total ----
    unsigned short* h    = (unsigned short*)d_ws;                  // NN*H bf16
    unsigned short* m    = h + (size_t)NN * H;                     // NN*H bf16
    unsigned short* aggB = m + (size_t)NN * H;                     // NN*H bf16
    unsigned short* tB   = aggB + (size_t)NN * H;                  // NN*H bf16
    float* stats_part    = (float*)(tB + (size_t)NN * H);          // NSPLIT*256
    float* coef          = stats_part + NSPLIT * 256;              // 256
    unsigned short* Wf   = (unsigned short*)(coef + 256);          // 11*16384 bf16
    unsigned short* pooledB = Wf + 11 * 16384;                     // NG*H bf16
    int* offsets = (int*)(pooledB + (size_t)NG * H);               // NOFF
    int* adj     = offsets + NOFF;                                 // NE
    int* gstart  = adj + NE;                                       // NG+1
    // transient CSR-build arrays overlaid in m (m is first written by layer-0
    // gemm2, strictly after the CSR build on the same stream)
    int* deg    = (int*)m;         // NN
    int* part   = deg + NN;        // NOFF
    int* bsum   = part + NOFF;     // 256
    int* cursor = bsum + 256;      // NN

    // weight prepack + CSR build (once; reused by all 4 layers)
    prepack_k<<<11, 256, 0, stream>>>(W1, W2, Wo1, Wo2, Wf);
    hipMemsetAsync(deg, 0, NN * sizeof(int), stream);
    hist_k<<<2344, 256, 0, stream>>>(ei, deg);
    scan1_k<<<NBLK, 256, 0, stream>>>(deg, part, bsum);
    scan2_k<<<1, 256, 0, stream>>>(bsum);
    scan3_k<<<NBLK, 256, 0, stream>>>(part, bsum, offsets, cursor);
    fill_k<<<2344, 256, 0, stream>>>(ei, cursor, adj);
    gbound_k<<<586, 256, 0, stream>>>(batch, gstart);

    encoder_k<<<75000, 256, 0, stream>>>(x, Wn, bn_b, h);

    for (int l = 0; l < 4; l++) {
        gather_k<<<18750, 256, 0, stream>>>(h, offsets, adj, eps, l, aggB, stats_part);
        gemm128f<true, true, false><<<2344, 256, 0, stream>>>(
            aggB, Wf + l * 16384, b1 + l * 128, tB, 128, NN, nullptr);
        gemm128f<false, true, true><<<2344, 256, 0, stream>>>(
            tB, Wf + (4 + l) * 16384, b2 + l * 128, m, 128, NN, stats_part);
        finalize_stats_k<<<1, 256, 0, stream>>>(stats_part, gamma + l * 128,
                                                beta + l * 128, coef, 1.f / NN);
        bn_apply_k<<<18750, 256, 0, stream>>>(m, coef, h);
    }

    pool_k<<<NG, 128, 0, stream>>>(h, gstart, pooledB);

    gemm128f<true, true, false><<<79, 256, 0, stream>>>(
        pooledB, Wf + 8 * 16384, bo1, tB, 128, NG, nullptr);
    gemm128f<false, false, false><<<79, 256, 0, stream>>>(
        tB, Wf + 9 * 16384, bo2, out, 256, NG, nullptr);
    gemm128f<false, false, false><<<79, 256, 0, stream>>>(
        tB, Wf + 10 * 16384, bo2 + 128, out + 128, 256, NG, nullptr);
}

// Round 10
// 709.905 us; speedup vs baseline: 1.7011x; 1.0829x over previous
//
#include <hip/hip_runtime.h>

#define NN 150000
#define NE 600000
#define NG 5000
#define H 128
#define NOFF (NN + 1)
#define NBLK 147   // ceil(150001 / 1024)
#define NSPLIT 64  // stats_part split factor

typedef short bf16x8 __attribute__((ext_vector_type(8)));
typedef float f32x4 __attribute__((ext_vector_type(4)));

__device__ __forceinline__ unsigned short f2bf(float f) {
    unsigned u = __builtin_bit_cast(unsigned, f);
    u += 0x7fffu + ((u >> 16) & 1u);
    return (unsigned short)(u >> 16);
}
__device__ __forceinline__ float bf2f(unsigned short u) {
    return __builtin_bit_cast(float, (unsigned)u << 16);
}

// h = bf16(x @ Wn + bn_b)   [NN,6]@[6,H]
__global__ __launch_bounds__(256) void encoder_k(const float* __restrict__ x,
                                                 const float* __restrict__ Wn,
                                                 const float* __restrict__ bn_b,
                                                 unsigned short* __restrict__ h) {
    int t = blockIdx.x * 256 + threadIdx.x;   // over NN*H
    int i = t >> 7, j = t & 127;
    float acc = bn_b[j];
#pragma unroll
    for (int k = 0; k < 6; k++) acc += x[i * 6 + k] * Wn[k * H + j];
    h[t] = f2bf(acc);
}

// ---------- weight prepack: bf16, MFMA-fragment order ----------
// mat m in [0,11): 0-3 W1[l], 4-7 W2[l], 8 Wo1, 9 Wo2 cols 0-127, 10 Wo2 cols 128-255
// chunk flat=(c*4+kk)*64+lane holds 8 shorts: W^T[n=c*16+(lane&15)][k=kk*32+(lane>>4)*8 .. +8]
__global__ __launch_bounds__(256) void prepack_k(const float* __restrict__ W1,
                                                 const float* __restrict__ W2,
                                                 const float* __restrict__ Wo1,
                                                 const float* __restrict__ Wo2,
                                                 unsigned short* __restrict__ Wf) {
    int m = blockIdx.x;
    const float* W; int ld, col0;
    if (m < 4)       { W = W1 + m * 16384;      ld = 128; col0 = 0; }
    else if (m < 8)  { W = W2 + (m - 4) * 16384; ld = 128; col0 = 0; }
    else if (m == 8) { W = Wo1;                  ld = 128; col0 = 0; }
    else if (m == 9) { W = Wo2;                  ld = 256; col0 = 0; }
    else             { W = Wo2;                  ld = 256; col0 = 128; }
    unsigned short* dst = Wf + m * 16384;
    for (int flat = threadIdx.x; flat < 2048; flat += 256) {
        int c = flat >> 8, kk = (flat >> 6) & 3, lane = flat & 63;
        int n = col0 + c * 16 + (lane & 15);
        int k0 = kk * 32 + (lane >> 4) * 8;
        ushort4 lo, hi;
        lo.x = f2bf(W[(size_t)(k0 + 0) * ld + n]);
        lo.y = f2bf(W[(size_t)(k0 + 1) * ld + n]);
        lo.z = f2bf(W[(size_t)(k0 + 2) * ld + n]);
        lo.w = f2bf(W[(size_t)(k0 + 3) * ld + n]);
        hi.x = f2bf(W[(size_t)(k0 + 4) * ld + n]);
        hi.y = f2bf(W[(size_t)(k0 + 5) * ld + n]);
        hi.z = f2bf(W[(size_t)(k0 + 6) * ld + n]);
        hi.w = f2bf(W[(size_t)(k0 + 7) * ld + n]);
        *(ushort4*)&dst[flat * 8]     = lo;
        *(ushort4*)&dst[flat * 8 + 4] = hi;
    }
}

// ---------- CSR build: histogram -> exclusive scan -> fill ----------

__global__ __launch_bounds__(256) void hist_k(const int* __restrict__ ei,
                                              int* __restrict__ deg) {
    int e = blockIdx.x * 256 + threadIdx.x;
    if (e < NE) atomicAdd(&deg[ei[NE + e]], 1);
}

__global__ __launch_bounds__(256) void scan1_k(const int* __restrict__ deg,
                                               int* __restrict__ part,
                                               int* __restrict__ bsum) {
    __shared__ int ls[256];
    int tid = threadIdx.x;
    int base = blockIdx.x * 1024 + tid * 4;
    int v[4], s = 0;
#pragma unroll
    for (int j = 0; j < 4; j++) {
        int idx = base + j;
        v[j] = (idx < NN) ? deg[idx] : 0;
        s += v[j];
    }
    ls[tid] = s;
    __syncthreads();
    for (int off = 1; off < 256; off <<= 1) {
        int t2 = (tid >= off) ? ls[tid - off] : 0;
        __syncthreads();
        if (tid >= off) ls[tid] += t2;
        __syncthreads();
    }
    int run = ls[tid] - s;
#pragma unroll
    for (int j = 0; j < 4; j++) {
        int idx = base + j;
        if (idx < NOFF) part[idx] = run;
        run += v[j];
    }
    if (tid == 255) bsum[blockIdx.x] = ls[255];
}

__global__ __launch_bounds__(256) void scan2_k(int* __restrict__ bsum) {
    __shared__ int ls[256];
    int tid = threadIdx.x;
    int v = (tid < NBLK) ? bsum[tid] : 0;
    ls[tid] = v;
    __syncthreads();
    for (int off = 1; off < 256; off <<= 1) {
        int t2 = (tid >= off) ? ls[tid - off] : 0;
        __syncthreads();
        if (tid >= off) ls[tid] += t2;
        __syncthreads();
    }
    if (tid < NBLK) bsum[tid] = ls[tid] - v;
}

__global__ __launch_bounds__(256) void scan3_k(const int* __restrict__ part,
                                               const int* __restrict__ bsum,
                                               int* __restrict__ offsets,
                                               int* __restrict__ cursor) {
    int tid = threadIdx.x;
    int base = blockIdx.x * 1024 + tid * 4;
    int bs = bsum[blockIdx.x];
#pragma unroll
    for (int j = 0; j < 4; j++) {
        int idx = base + j;
        if (idx < NOFF) {
            int o = part[idx] + bs;
            offsets[idx] = o;
            if (idx < NN) cursor[idx] = o;
        }
    }
}

__global__ __launch_bounds__(256) void fill_k(const int* __restrict__ ei,
                                              int* __restrict__ cursor,
                                              int* __restrict__ adj) {
    int e = blockIdx.x * 256 + threadIdx.x;
    if (e < NE) {
        int p = atomicAdd(&cursor[ei[NE + e]], 1);
        if (p >= 0 && p < NE) adj[p] = ei[e];
    }
}

// ---------- gather: agg = bf16((1+eps)*h + sum_{j->i} h[j]), fp32 accum ----------
__global__ __launch_bounds__(256) void gather_k(const unsigned short* __restrict__ h,
                                                const int* __restrict__ offsets,
                                                const int* __restrict__ adj,
                                                const float* __restrict__ eps, int l,
                                                unsigned short* __restrict__ agg,
                                                float* __restrict__ stats_part) {
    if (blockIdx.x < NSPLIT) stats_part[blockIdx.x * 256 + threadIdx.x] = 0.f;
    int t = blockIdx.x * 256 + threadIdx.x;   // NN*32, 4 cols per thread
    int i = t >> 5, q = t & 31;
    const ushort4* hp = (const ushort4*)h;
    float e = 1.f + eps[l];
    ushort4 sv = hp[(size_t)i * 32 + q];
    float a0 = bf2f(sv.x) * e, a1 = bf2f(sv.y) * e, a2 = bf2f(sv.z) * e, a3 = bf2f(sv.w) * e;
    int s0 = offsets[i], s1 = offsets[i + 1];
    for (int k = s0; k < s1; k++) {
        int src = adj[k];
        ushort4 v = hp[(size_t)src * 32 + q];
        a0 += bf2f(v.x); a1 += bf2f(v.y); a2 += bf2f(v.z); a3 += bf2f(v.w);
    }
    ushort4 o;
    o.x = f2bf(a0); o.y = f2bf(a1); o.z = f2bf(a2); o.w = f2bf(a3);
    ((ushort4*)agg)[(size_t)i * 32 + q] = o;
}

// ---------- fused MLP: m = bf16( relu(agg@W1+b1) @ W2 + b2 ), + BN stats ----------
// t-tile lives in LDS between the two MFMA phases; W2 restaged over W1.
__global__ __launch_bounds__(256) void mlp_k(const unsigned short* __restrict__ A,
                                             const unsigned short* __restrict__ Wf1,
                                             const unsigned short* __restrict__ Wf2,
                                             const float* __restrict__ b1,
                                             const float* __restrict__ b2,
                                             unsigned short* __restrict__ Cm, int M,
                                             float* __restrict__ stats_part) {
    __shared__ short Wlds[16384];      // fragment-order W (W1, then W2)
    __shared__ short Tlds[64 * 136];   // t tile, +8 short pad
    __shared__ float sst[256];
    int tid = threadIdx.x;
#pragma unroll
    for (int i = 0; i < 8; i++) {
        int flat = i * 256 + tid;
        ((bf16x8*)Wlds)[flat] = ((const bf16x8*)Wf1)[flat];
    }
    sst[tid] = 0.f;
    __syncthreads();

    int w = tid >> 6, lane = tid & 63;
    int quad = lane >> 4, lr = lane & 15;
    int rowA = blockIdx.x * 64 + w * 16 + lr;
    bool rowOK = rowA < M;
    const unsigned short* ap = A + (size_t)rowA * 128 + quad * 8;

    // phase 1: t = relu(agg @ W1 + b1)
    f32x4 acc[8];
#pragma unroll
    for (int c = 0; c < 8; c++) acc[c] = (f32x4){0.f, 0.f, 0.f, 0.f};
#pragma unroll
    for (int kk = 0; kk < 4; kk++) {
        bf16x8 af = rowOK ? *(const bf16x8*)(ap + kk * 32)
                          : (bf16x8){0, 0, 0, 0, 0, 0, 0, 0};
#pragma unroll
        for (int c = 0; c < 8; c++) {
            bf16x8 bf = ((const bf16x8*)Wlds)[(c * 4 + kk) * 64 + lane];
            acc[c] = __builtin_amdgcn_mfma_f32_16x16x32_bf16(af, bf, acc[c], 0, 0, 0);
        }
    }
    // write t-tile to LDS (bf16); rows >= M carry garbage but are masked later
    int rl0 = w * 16 + quad * 4;   // local row base
#pragma unroll
    for (int c = 0; c < 8; c++) {
        int col = c * 16 + lr;
        float bv = b1[col];
#pragma unroll
        for (int r = 0; r < 4; r++)
            Tlds[(rl0 + r) * 136 + col] = (short)f2bf(fmaxf(acc[c][r] + bv, 0.f));
    }
    __syncthreads();   // t-tile complete; W1 reads done
#pragma unroll
    for (int i = 0; i < 8; i++) {
        int flat = i * 256 + tid;
        ((bf16x8*)Wlds)[flat] = ((const bf16x8*)Wf2)[flat];
    }
    __syncthreads();   // W2 staged

    // phase 2: m = t @ W2 + b2
#pragma unroll
    for (int c = 0; c < 8; c++) acc[c] = (f32x4){0.f, 0.f, 0.f, 0.f};
#pragma unroll
    for (int kk = 0; kk < 4; kk++) {
        bf16x8 af = *(const bf16x8*)&Tlds[(w * 16 + lr) * 136 + kk * 32 + quad * 8];
#pragma unroll
        for (int c = 0; c < 8; c++) {
            bf16x8 bf = ((const bf16x8*)Wlds)[(c * 4 + kk) * 64 + lane];
            acc[c] = __builtin_amdgcn_mfma_f32_16x16x32_bf16(af, bf, acc[c], 0, 0, 0);
        }
    }

    int r0 = blockIdx.x * 64 + w * 16 + quad * 4;
#pragma unroll
    for (int c = 0; c < 8; c++) {
        int col = c * 16 + lr;
        float bv = b2[col];
        float ls = 0.f, ls2 = 0.f;
#pragma unroll
        for (int r = 0; r < 4; r++) {
            int row = r0 + r;
            if (row < M) {
                float v = acc[c][r] + bv;
                Cm[(size_t)row * H + col] = f2bf(v);
                ls += v; ls2 += v * v;
            }
        }
        ls  += __shfl_xor(ls, 16);  ls  += __shfl_xor(ls, 32);
        ls2 += __shfl_xor(ls2, 16); ls2 += __shfl_xor(ls2, 32);
        if (quad == 0) {
            atomicAdd(&sst[col], ls);
            atomicAdd(&sst[128 + col], ls2);
        }
    }
    __syncthreads();
    atomicAdd(&stats_part[(blockIdx.x & (NSPLIT - 1)) * 256 + tid], sst[tid]);
}

// C[M,128] = op(bf16 A[M,128] @ Wf + bias); Wf prepacked fragment-order bf16.
template <bool RELU, bool OBF16>
__global__ __launch_bounds__(256) void gemm128f(const unsigned short* __restrict__ A,
                                                const unsigned short* __restrict__ Wf,
                                                const float* __restrict__ bias,
                                                void* __restrict__ Cv, int ldC, int M) {
    __shared__ short Wlds[16384];
    int tid = threadIdx.x;
#pragma unroll
    for (int i = 0; i < 8; i++) {
        int flat = i * 256 + tid;
        ((bf16x8*)Wlds)[flat] = ((const bf16x8*)Wf)[flat];
    }
    __syncthreads();

    int w = tid >> 6, lane = tid & 63;
    int quad = lane >> 4, lr = lane & 15;
    int rowA = blockIdx.x * 64 + w * 16 + lr;
    bool rowOK = rowA < M;
    const unsigned short* ap = A + (size_t)rowA * 128 + quad * 8;

    f32x4 acc[8];
#pragma unroll
    for (int c = 0; c < 8; c++) acc[c] = (f32x4){0.f, 0.f, 0.f, 0.f};
#pragma unroll
    for (int kk = 0; kk < 4; kk++) {
        bf16x8 af = rowOK ? *(const bf16x8*)(ap + kk * 32)
                          : (bf16x8){0, 0, 0, 0, 0, 0, 0, 0};
#pragma unroll
        for (int c = 0; c < 8; c++) {
            bf16x8 bf = ((const bf16x8*)Wlds)[(c * 4 + kk) * 64 + lane];
            acc[c] = __builtin_amdgcn_mfma_f32_16x16x32_bf16(af, bf, acc[c], 0, 0, 0);
        }
    }

    int r0 = blockIdx.x * 64 + w * 16 + quad * 4;
#pragma unroll
    for (int c = 0; c < 8; c++) {
        int col = c * 16 + lr;
        float bv = bias[col];
#pragma unroll
        for (int r = 0; r < 4; r++) {
            int row = r0 + r;
            if (row < M) {
                float v = acc[c][r] + bv;
                if (RELU) v = fmaxf(v, 0.f);
                if (OBF16)
                    ((unsigned short*)Cv)[(size_t)row * ldC + col] = f2bf(v);
                else
                    ((float*)Cv)[(size_t)row * ldC + col] = v;
            }
        }
    }
}

// reduce stats_part -> coef[c]=gamma*istd, coef[128+c]=beta-mu*gamma*istd
__global__ __launch_bounds__(256) void finalize_stats_k(const float* __restrict__ stats_part,
                                                        const float* __restrict__ gamma,
                                                        const float* __restrict__ beta,
                                                        float* __restrict__ coef, float invN) {
    __shared__ float ls[256];
    int t = threadIdx.x;
    float s = 0.f;
    for (int p = 0; p < NSPLIT; p++) s += stats_part[p * 256 + t];
    ls[t] = s;
    __syncthreads();
    if (t < 128) {
        float mu = ls[t] * invN;
        float var = ls[128 + t] * invN - mu * mu;
        float a = gamma[t] * rsqrtf(var + 1e-5f);
        coef[t] = a;
        coef[128 + t] = beta[t] - mu * a;
    }
}

// h = bf16(relu(m*a + b) + h)   (m stored bf16)
__global__ __launch_bounds__(256) void bn_apply_k(const unsigned short* __restrict__ m,
                                                  const float* __restrict__ coef,
                                                  unsigned short* __restrict__ h) {
    int t = blockIdx.x * 256 + threadIdx.x;   // NN*32, 4 cols per thread
    int c4 = t & 31;
    float4 a = ((const float4*)coef)[c4];
    float4 b = ((const float4*)coef)[32 + c4];
    ushort4 mv = ((const ushort4*)m)[t];
    ushort4 hv = ((const ushort4*)h)[t];
    float h0 = bf2f(hv.x) + fmaxf(bf2f(mv.x) * a.x + b.x, 0.f);
    float h1 = bf2f(hv.y) + fmaxf(bf2f(mv.y) * a.y + b.y, 0.f);
    float h2 = bf2f(hv.z) + fmaxf(bf2f(mv.z) * a.z + b.z, 0.f);
    float h3 = bf2f(hv.w) + fmaxf(bf2f(mv.w) * a.w + b.w, 0.f);
    ushort4 o;
    o.x = f2bf(h0); o.y = f2bf(h1); o.z = f2bf(h2); o.w = f2bf(h3);
    ((ushort4*)h)[t] = o;
}

// ---------- pooling (batch is sorted) ----------

__global__ __launch_bounds__(256) void gbound_k(const int* __restrict__ batch,
                                                int* __restrict__ gstart) {
    int i = blockIdx.x * 256 + threadIdx.x;
    if (i >= NN) return;
    int b = batch[i];
    int prev = (i == 0) ? -1 : batch[i - 1];
    for (int g = prev + 1; g <= b; g++) gstart[g] = i;
    if (i == NN - 1) {
        for (int g = b + 1; g <= NG; g++) gstart[g] = NN;
    }
}

// one block per graph: mean over its node rows -> bf16 pooled
__global__ __launch_bounds__(128) void pool_k(const unsigned short* __restrict__ h,
                                              const int* __restrict__ gstart,
                                              unsigned short* __restrict__ pooled) {
    int g = blockIdx.x, col = threadIdx.x;
    int r0 = gstart[g], r1 = gstart[g + 1];
    float s = 0.f;
    for (int r = r0; r < r1; r++) s += bf2f(h[(size_t)r * H + col]);
    pooled[(size_t)g * H + col] = f2bf(s / fmaxf((float)(r1 - r0), 1.f));
}

extern "C" void kernel_launch(void* const* d_in, const int* in_sizes, int n_in,
                              void* d_out, int out_size, void* d_ws, size_t ws_size,
                              hipStream_t stream) {
    const float* x     = (const float*)d_in[0];
    const int*   ei    = (const int*)d_in[1];
    const int*   batch = (const int*)d_in[2];
    const float* Wn    = (const float*)d_in[3];
    const float* bn_b  = (const float*)d_in[4];
    const float* eps   = (const float*)d_in[5];
    const float* W1    = (const float*)d_in[6];
    const float* b1    = (const float*)d_in[7];
    const float* W2    = (const float*)d_in[8];
    const float* b2    = (const float*)d_in[9];
    const float* gamma = (const float*)d_in[10];
    const float* beta  = (const float*)d_in[11];
    const float* Wo1   = (const float*)d_in[12];
    const float* bo1   = (const float*)d_in[13];
    const float* Wo2   = (const float*)d_in[14];
    const float* bo2   = (const float*)d_in[15];
    float* out = (float*)d_out;

    // ---- workspace: ~120 MB total ----
    unsigned short* h    = (unsigned short*)d_ws;                  // NN*H bf16
    unsigned short* m    = h + (size_t)NN * H;                     // NN*H bf16
    unsigned short* aggB = m + (size_t)NN * H;                     // NN*H bf16
    unsigned short* tB   = aggB + (size_t)NN * H;                  // NG*H bf16 scratch (small use)
    float* stats_part    = (float*)(tB + (size_t)NG * H);          // NSPLIT*256
    float* coef          = stats_part + NSPLIT * 256;              // 256
    unsigned short* Wf   = (unsigned short*)(coef + 256);          // 11*16384 bf16
    unsigned short* pooledB = Wf + 11 * 16384;                     // NG*H bf16
    int* offsets = (int*)(pooledB + (size_t)NG * H);               // NOFF
    int* adj     = offsets + NOFF;                                 // NE
    int* gstart  = adj + NE;                                       // NG+1
    // transient CSR-build arrays overlaid in m (m is first written by layer-0
    // mlp_k, strictly after the CSR build on the same stream)
    int* deg    = (int*)m;         // NN
    int* part   = deg + NN;        // NOFF
    int* bsum   = part + NOFF;     // 256
    int* cursor = bsum + 256;      // NN

    // weight prepack + CSR build (once; reused by all 4 layers)
    prepack_k<<<11, 256, 0, stream>>>(W1, W2, Wo1, Wo2, Wf);
    hipMemsetAsync(deg, 0, NN * sizeof(int), stream);
    hist_k<<<2344, 256, 0, stream>>>(ei, deg);
    scan1_k<<<NBLK, 256, 0, stream>>>(deg, part, bsum);
    scan2_k<<<1, 256, 0, stream>>>(bsum);
    scan3_k<<<NBLK, 256, 0, stream>>>(part, bsum, offsets, cursor);
    fill_k<<<2344, 256, 0, stream>>>(ei, cursor, adj);
    gbound_k<<<586, 256, 0, stream>>>(batch, gstart);

    encoder_k<<<75000, 256, 0, stream>>>(x, Wn, bn_b, h);

    for (int l = 0; l < 4; l++) {
        gather_k<<<18750, 256, 0, stream>>>(h, offsets, adj, eps, l, aggB, stats_part);
        mlp_k<<<2344, 256, 0, stream>>>(aggB, Wf + l * 16384, Wf + (4 + l) * 16384,
                                        b1 + l * 128, b2 + l * 128, m, NN, stats_part);
        finalize_stats_k<<<1, 256, 0, stream>>>(stats_part, gamma + l * 128,
                                                beta + l * 128, coef, 1.f / NN);
        bn_apply_k<<<18750, 256, 0, stream>>>(m, coef, h);
    }

    pool_k<<<NG, 128, 0, stream>>>(h, gstart, pooledB);

    gemm128f<true, true><<<79, 256, 0, stream>>>(
        pooledB, Wf + 8 * 16384, bo1, tB, 128, NG);
    gemm128f<false, false><<<79, 256, 0, stream>>>(
        tB, Wf + 9 * 16384, bo2, out, 256, NG);
    gemm128f<false, false><<<79, 256, 0, stream>>>(
        tB, Wf + 10 * 16384, bo2 + 128, out + 128, 256, NG);
}